// Round 7
// baseline (384.451 us; speedup 1.0000x reference)
//
#include <hip/hip_runtime.h>
#include <hip/hip_bf16.h>
#include <math.h>

#define T_TOK 1024
#define H_DIM 2048
#define I_DIM 768
#define E_NUM 32
#define K_TOP 8
#define BK 32
#define GRID_P 1024   // persistent grid: 256 CUs x up to 4 blocks

typedef __bf16 bf16x8 __attribute__((ext_vector_type(8)));
typedef float  f32x4  __attribute__((ext_vector_type(4)));

__device__ __forceinline__ bf16x8 cvt2_bf16(const f32x4 a, const f32x4 b) {
    bf16x8 r;
    r[0] = (__bf16)a[0]; r[1] = (__bf16)a[1]; r[2] = (__bf16)a[2]; r[3] = (__bf16)a[3];
    r[4] = (__bf16)b[0]; r[5] = (__bf16)b[1]; r[6] = (__bf16)b[2]; r[7] = (__bf16)b[3];
    return r;
}

// LDS fragment-order layout: tile is (rows x 32k) bf16, stored as 16-row
// subtiles of 512 elems; element (r,k) at (r>>4)*512 + (k>>3)*128 + (r&15)*8 + (k&7).
// A wave's MFMA fragment read = subtile base + lane*16B -> linear, conflict-free.
__device__ __forceinline__ int frag_off(int r, int kgrp8) {
    return (r >> 4) * 512 + kgrp8 * 128 + (r & 15) * 8;
}

// ---------------- fast zero of d_out (replaces slow graph memset node) ------
__global__ __launch_bounds__(256) void zero_kernel(float* __restrict__ p)
{
    const int i = (blockIdx.x * 256 + threadIdx.x) * 4;
    *(f32x4*)(p + i) = f32x4{0.f, 0.f, 0.f, 0.f};
}

// ---------------- x fp32 -> bf16 pre-convert --------------------------------
__global__ __launch_bounds__(256) void cvtx_kernel(
    const float* __restrict__ x, __bf16* __restrict__ xb)
{
    const int i = (blockIdx.x * 256 + threadIdx.x) * 8;
    const f32x4 a = *(const f32x4*)(x + i);
    const f32x4 b = *(const f32x4*)(x + i + 4);
    *(bf16x8*)(xb + i) = cvt2_bf16(a, b);
}

// ---------------- Router: logits -> top-8 -> normalized weights -------------
__global__ __launch_bounds__(256) void router_kernel(
    const float* __restrict__ x, const float* __restrict__ gw,
    float* __restrict__ wdense, unsigned int* __restrict__ masks)
{
    const int t = blockIdx.x;
    const int tid = threadIdx.x;
    __shared__ float part[256];
    __shared__ float logits[E_NUM];
    const int e = tid & 31;
    const int chunk = tid >> 5;
    const float* xr = x + (size_t)t * H_DIM;
    const float* gr = gw + (size_t)e * H_DIM;
    const int base = chunk * (H_DIM / 8);
    float s = 0.f;
    for (int h = 0; h < H_DIM / 8; h += 4) {
        const f32x4 xv = *reinterpret_cast<const f32x4*>(xr + base + h);
        const f32x4 gv = *reinterpret_cast<const f32x4*>(gr + base + h);
        s += xv[0]*gv[0] + xv[1]*gv[1] + xv[2]*gv[2] + xv[3]*gv[3];
    }
    part[tid] = s;
    __syncthreads();
    if (tid < E_NUM) {
        float tot = 0.f;
        for (int c = 0; c < 8; ++c) tot += part[c * 32 + tid];
        logits[tid] = tot;
    }
    __syncthreads();
    if (tid == 0) {
        float l[E_NUM];
        for (int i = 0; i < E_NUM; ++i) {
            l[i] = logits[i];
            wdense[(size_t)t * E_NUM + i] = 0.f;
        }
        unsigned mask = 0;
        int   idx[K_TOP];
        float lv[K_TOP];
        for (int k = 0; k < K_TOP; ++k) {
            float best = -1e30f; int bi = 0;
            for (int i = 0; i < E_NUM; ++i)
                if (!((mask >> i) & 1u) && l[i] > best) { best = l[i]; bi = i; }
            mask |= (1u << bi); idx[k] = bi; lv[k] = best;
        }
        const float m = lv[0];
        float den = 0.f;
        for (int k = 0; k < K_TOP; ++k) den += expf(lv[k] - m);
        for (int k = 0; k < K_TOP; ++k)
            wdense[(size_t)t * E_NUM + idx[k]] = expf(lv[k] - m) / den;
        masks[t] = mask;
    }
}

// ---------------- Build compacted per-expert token lists --------------------
__global__ __launch_bounds__(256) void count_kernel(
    const unsigned int* __restrict__ masks, int* __restrict__ cnt)
{
    const int e = blockIdx.x;
    const int tid = threadIdx.x;
    int c = 0;
    for (int t = tid; t < T_TOK; t += 256) c += (masks[t] >> e) & 1u;
    __shared__ int red[256];
    red[tid] = c; __syncthreads();
    for (int s = 128; s > 0; s >>= 1) {
        if (tid < s) red[tid] += red[tid + s];
        __syncthreads();
    }
    if (tid == 0) cnt[e] = red[0];
}

// scan + live-tile table: tbl[0]=ntiles, tbl[1+i] = (e<<8)|zt  (128-token tiles)
__global__ void scan_kernel(const int* __restrict__ cnt, int* __restrict__ off,
                            int* __restrict__ tbl)
{
    if (threadIdx.x == 0 && blockIdx.x == 0) {
        int r = 0, nt = 0;
        for (int e = 0; e < E_NUM; ++e) {
            off[e] = r;
            const int c = cnt[e];
            r += c;
            const int t = (c + 127) >> 7;
            for (int z = 0; z < t; ++z) tbl[1 + nt++] = (e << 8) | z;
        }
        tbl[0] = nt;
    }
}

__global__ __launch_bounds__(256) void fill_kernel(
    const unsigned int* __restrict__ masks, const float* __restrict__ wdense,
    const int* __restrict__ off, int* __restrict__ tok, float* __restrict__ wgt)
{
    const int e = blockIdx.x;
    const int tid = threadIdx.x;
    const int PER = T_TOK / 256;
    int sel[PER]; int c = 0;
    for (int i = 0; i < PER; ++i) {
        const int t = tid * PER + i;
        sel[i] = (masks[t] >> e) & 1u;
        c += sel[i];
    }
    __shared__ int s[256];
    s[tid] = c; __syncthreads();
    if (tid == 0) {
        int r = 0;
        for (int j = 0; j < 256; ++j) { int v = s[j]; s[j] = r; r += v; }
    }
    __syncthreads();
    int pos = off[e] + s[tid];
    for (int i = 0; i < PER; ++i) {
        if (sel[i]) {
            const int t = tid * PER + i;
            tok[pos] = t;
            wgt[pos] = wdense[(size_t)t * E_NUM + e];
            pos++;
        }
    }
}

// Phase macro for gemm1: read buf P, prefetch L(scur+2) into regset P,
// write regset Q (=L(scur+1)) into buf Q. Raw barrier, NO vmcnt drain.
#define G1_PHASE(P, Q)                                                         \
  {                                                                            \
    if (scur + 2 < NS) {                                                       \
      const int kk = (scur + 2) * BK;                                          \
      pa##P##_0 = *(const bf16x8*)(xp + kk);                                   \
      pa##P##_1 = *(const bf16x8*)(xp + kk + 8);                               \
      pb##P##_0 = *(const f32x4*)(wp + kk);                                    \
      pb##P##_1 = *(const f32x4*)(wp + kk + 4);                                \
      pb##P##_2 = *(const f32x4*)(wp + kk + 8);                                \
      pb##P##_3 = *(const f32x4*)(wp + kk + 12);                               \
    }                                                                          \
    bf16x8 af[4], bfr[4];                                                      \
    _Pragma("unroll")                                                          \
    for (int m = 0; m < 4; ++m)                                                \
      af[m] = *(const bf16x8*)&As[P][((wm >> 4) + m) * 512 + lane * 8];        \
    _Pragma("unroll")                                                          \
    for (int n = 0; n < 4; ++n)                                                \
      bfr[n] = *(const bf16x8*)&Bs[P][(wn * 4 + n) * 512 + lane * 8];          \
    _Pragma("unroll")                                                          \
    for (int m = 0; m < 4; ++m)                                                \
      _Pragma("unroll")                                                        \
      for (int n = 0; n < 4; ++n)                                              \
        acc[m][n] = __builtin_amdgcn_mfma_f32_16x16x32_bf16(af[m], bfr[n],     \
                                                            acc[m][n], 0,0,0); \
    if (scur + 1 < NS) {                                                       \
      *(bf16x8*)&As[Q][wo]       = pa##Q##_0;                                  \
      *(bf16x8*)&As[Q][wo + 128] = pa##Q##_1;                                  \
      *(bf16x8*)&Bs[Q][wo]       = cvt2_bf16(pb##Q##_0, pb##Q##_1);            \
      *(bf16x8*)&Bs[Q][wo + 128] = cvt2_bf16(pb##Q##_2, pb##Q##_3);            \
    }                                                                          \
    asm volatile("s_waitcnt lgkmcnt(0)" ::: "memory");                         \
    __builtin_amdgcn_s_barrier();                                              \
    ++scur;                                                                    \
  }

// ---------------- GEMM1: act = silu(x @ w1^T) * (x @ w3^T) ------------------
// Persistent: work w = tile*12 + nidx. Tile: 128 tok x 128 Brows
// (Brows: [0:32)=gate lo, [32:64)=up lo, [64:96)=gate hi, [96:128)=up hi).
// Wave (2Mx2N): 64 tok x 64 Brows -> acc[4][4]; n=0,1 gate, n=2,3 up.
__global__ __launch_bounds__(256, 3) void gemm1_kernel(
    const __bf16* __restrict__ xb, const float* __restrict__ w13,
    const int* __restrict__ tok, const int* __restrict__ cnt,
    const int* __restrict__ off, const int* __restrict__ tbl,
    unsigned short* __restrict__ act)
{
    __shared__ __bf16 As[2][4096];
    __shared__ __bf16 Bs[2][4096];
    const int tid  = threadIdx.x;
    const int wid  = tid >> 6;
    const int lane = tid & 63;
    const int wm = (wid >> 1) * 64;
    const int wn = (wid & 1);
    const int lrow = lane & 15;
    const int sr = tid >> 1;
    const int kh = tid & 1;
    const int wo = frag_off(sr, kh * 2);
    const int NS = H_DIM / BK;   // 64

    const int W = tbl[0] * 12;
    for (int w = blockIdx.x; w < W; w += gridDim.x) {
        const int ti   = w / 12;
        const int nidx = w - ti * 12;
        const int ez = tbl[1 + ti];
        const int e  = ez >> 8;
        const int m0 = (ez & 255) * 128;
        const int c  = cnt[e];
        const int o  = off[e];
        const int n0 = nidx * 64;

        int rA = m0 + sr; rA = rA < c ? rA : c - 1;
        const __bf16* xp = xb + (size_t)tok[o + rA] * H_DIM + kh * 16;
        const int grp = sr >> 5;
        const int wrow = (grp & 1) * I_DIM + n0 + (grp >> 1) * 32 + (sr & 31);
        const float* wp = w13 + (size_t)e * (2 * I_DIM) * H_DIM
                              + (size_t)wrow * H_DIM + kh * 16;

        bf16x8 pa0_0, pa0_1, pa1_0, pa1_1;
        f32x4  pb0_0, pb0_1, pb0_2, pb0_3, pb1_0, pb1_1, pb1_2, pb1_3;
        f32x4  acc[4][4] = {};

        // prologue: issue L0 (set0) and L1 (set1); write L0 -> buf0
        pa0_0 = *(const bf16x8*)(xp);
        pa0_1 = *(const bf16x8*)(xp + 8);
        pb0_0 = *(const f32x4*)(wp);
        pb0_1 = *(const f32x4*)(wp + 4);
        pb0_2 = *(const f32x4*)(wp + 8);
        pb0_3 = *(const f32x4*)(wp + 12);
        pa1_0 = *(const bf16x8*)(xp + BK);
        pa1_1 = *(const bf16x8*)(xp + BK + 8);
        pb1_0 = *(const f32x4*)(wp + BK);
        pb1_1 = *(const f32x4*)(wp + BK + 4);
        pb1_2 = *(const f32x4*)(wp + BK + 8);
        pb1_3 = *(const f32x4*)(wp + BK + 12);
        *(bf16x8*)&As[0][wo]       = pa0_0;
        *(bf16x8*)&As[0][wo + 128] = pa0_1;
        *(bf16x8*)&Bs[0][wo]       = cvt2_bf16(pb0_0, pb0_1);
        *(bf16x8*)&Bs[0][wo + 128] = cvt2_bf16(pb0_2, pb0_3);
        asm volatile("s_waitcnt lgkmcnt(0)" ::: "memory");
        __builtin_amdgcn_s_barrier();

        int scur = 0;
        for (int it = 0; it < NS; it += 2) {
            G1_PHASE(0, 1)
            G1_PHASE(1, 0)
        }

        // epilogue: n=0,1 gate, n=2,3 up; icol = n0 + wn*32 + n*16 + lrow
#pragma unroll
        for (int m = 0; m < 4; ++m)
#pragma unroll
            for (int n = 0; n < 2; ++n)
#pragma unroll
                for (int i = 0; i < 4; ++i) {
                    const int row = m0 + wm + m * 16 + (lane >> 4) * 4 + i;
                    if (row < c) {
                        const int icol = n0 + wn * 32 + n * 16 + lrow;
                        const float g = acc[m][n][i];
                        const float u = acc[m][n + 2][i];
                        const float a = (g / (1.f + expf(-g))) * u;
                        act[(size_t)(o + row) * I_DIM + icol] =
                            __builtin_bit_cast(unsigned short, (__bf16)a);
                    }
                }
    }
}

// Phase macro for gemm2 (A already bf16).
#define G2_PHASE(P, Q)                                                         \
  {                                                                            \
    if (scur + 2 < NS) {                                                       \
      const int kk = (scur + 2) * BK;                                          \
      qa##P##_0 = *(const bf16x8*)(ap + kk);                                   \
      qa##P##_1 = *(const bf16x8*)(ap + kk + 8);                               \
      qb##P##_0 = *(const f32x4*)(wp + kk);                                    \
      qb##P##_1 = *(const f32x4*)(wp + kk + 4);                                \
      qb##P##_2 = *(const f32x4*)(wp + kk + 8);                                \
      qb##P##_3 = *(const f32x4*)(wp + kk + 12);                               \
    }                                                                          \
    bf16x8 af[4], bfr[4];                                                      \
    _Pragma("unroll")                                                          \
    for (int m = 0; m < 4; ++m)                                                \
      af[m] = *(const bf16x8*)&As[P][((wm >> 4) + m) * 512 + lane * 8];        \
    _Pragma("unroll")                                                          \
    for (int n = 0; n < 4; ++n)                                                \
      bfr[n] = *(const bf16x8*)&Bs[P][(wn * 4 + n) * 512 + lane * 8];          \
    _Pragma("unroll")                                                          \
    for (int m = 0; m < 4; ++m)                                                \
      _Pragma("unroll")                                                        \
      for (int n = 0; n < 4; ++n)                                              \
        acc[m][n] = __builtin_amdgcn_mfma_f32_16x16x32_bf16(af[m], bfr[n],     \
                                                            acc[m][n], 0,0,0); \
    if (scur + 1 < NS) {                                                       \
      *(bf16x8*)&As[Q][wo]       = qa##Q##_0;                                  \
      *(bf16x8*)&As[Q][wo + 128] = qa##Q##_1;                                  \
      *(bf16x8*)&Bs[Q][wo]       = cvt2_bf16(qb##Q##_0, qb##Q##_1);            \
      *(bf16x8*)&Bs[Q][wo + 128] = cvt2_bf16(qb##Q##_2, qb##Q##_3);            \
    }                                                                          \
    asm volatile("s_waitcnt lgkmcnt(0)" ::: "memory");                         \
    __builtin_amdgcn_s_barrier();                                              \
    ++scur;                                                                    \
  }

// ---------------- GEMM2: out[t] += wgt * (act @ w2^T) -----------------------
// Persistent: work w = tile*16 + nidx. Tile: 128 tok x 128 H-cols.
__global__ __launch_bounds__(256, 3) void gemm2_kernel(
    const unsigned short* __restrict__ act, const float* __restrict__ w2,
    const int* __restrict__ tok, const float* __restrict__ wgt,
    const int* __restrict__ cnt, const int* __restrict__ off,
    const int* __restrict__ tbl, float* __restrict__ out)
{
    __shared__ __bf16 As[2][4096];
    __shared__ __bf16 Bs[2][4096];
    const int tid  = threadIdx.x;
    const int wid  = tid >> 6;
    const int lane = tid & 63;
    const int wm = (wid >> 1) * 64;
    const int wn = (wid & 1);
    const int lrow = lane & 15;
    const int sr = tid >> 1;
    const int kh = tid & 1;
    const int wo = frag_off(sr, kh * 2);
    const int NS = I_DIM / BK;   // 24

    const int W = tbl[0] * 16;
    for (int w = blockIdx.x; w < W; w += gridDim.x) {
        const int ti   = w >> 4;
        const int nidx = w & 15;
        const int ez = tbl[1 + ti];
        const int e  = ez >> 8;
        const int m0 = (ez & 255) * 128;
        const int c  = cnt[e];
        const int o  = off[e];
        const int n0 = nidx * 128;

        int rA = m0 + sr; rA = rA < c ? rA : c - 1;
        const __bf16* ap = (const __bf16*)act + (size_t)(o + rA) * I_DIM + kh * 16;
        const float* wp = w2 + (size_t)e * H_DIM * I_DIM
                             + (size_t)(n0 + sr) * I_DIM + kh * 16;

        bf16x8 qa0_0, qa0_1, qa1_0, qa1_1;
        f32x4  qb0_0, qb0_1, qb0_2, qb0_3, qb1_0, qb1_1, qb1_2, qb1_3;
        f32x4  acc[4][4] = {};

        qa0_0 = *(const bf16x8*)(ap);
        qa0_1 = *(const bf16x8*)(ap + 8);
        qb0_0 = *(const f32x4*)(wp);
        qb0_1 = *(const f32x4*)(wp + 4);
        qb0_2 = *(const f32x4*)(wp + 8);
        qb0_3 = *(const f32x4*)(wp + 12);
        qa1_0 = *(const bf16x8*)(ap + BK);
        qa1_1 = *(const bf16x8*)(ap + BK + 8);
        qb1_0 = *(const f32x4*)(wp + BK);
        qb1_1 = *(const f32x4*)(wp + BK + 4);
        qb1_2 = *(const f32x4*)(wp + BK + 8);
        qb1_3 = *(const f32x4*)(wp + BK + 12);
        *(bf16x8*)&As[0][wo]       = qa0_0;
        *(bf16x8*)&As[0][wo + 128] = qa0_1;
        *(bf16x8*)&Bs[0][wo]       = cvt2_bf16(qb0_0, qb0_1);
        *(bf16x8*)&Bs[0][wo + 128] = cvt2_bf16(qb0_2, qb0_3);
        asm volatile("s_waitcnt lgkmcnt(0)" ::: "memory");
        __builtin_amdgcn_s_barrier();

        int scur = 0;
        for (int it = 0; it < NS; it += 2) {
            G2_PHASE(0, 1)
            G2_PHASE(1, 0)
        }

#pragma unroll
        for (int m = 0; m < 4; ++m)
#pragma unroll
            for (int n = 0; n < 4; ++n)
#pragma unroll
                for (int i = 0; i < 4; ++i) {
                    const int row = m0 + wm + m * 16 + (lane >> 4) * 4 + i;
                    if (row < c) {
                        const int t = tok[o + row];
                        const float wv = wgt[o + row];
                        const int hcol = n0 + wn * 64 + n * 16 + lrow;
                        atomicAdd(&out[(size_t)t * H_DIM + hcol], wv * acc[m][n][i]);
                    }
                }
    }
}

// ---------------- Launch ----------------------------------------------------
extern "C" void kernel_launch(void* const* d_in, const int* in_sizes, int n_in,
                              void* d_out, int out_size, void* d_ws, size_t ws_size,
                              hipStream_t stream)
{
    const float* x   = (const float*)d_in[0];
    const float* gw  = (const float*)d_in[1];
    const float* w13 = (const float*)d_in[2];
    const float* w2  = (const float*)d_in[3];
    float* out = (float*)d_out;

    char* ws = (char*)d_ws;
    float*          wdense = (float*)(ws + 0x00000);
    unsigned int*   masks  = (unsigned int*)(ws + 0x20000);
    int*            cnt    = (int*)(ws + 0x21000);
    int*            off    = (int*)(ws + 0x21800);
    int*            tbl    = (int*)(ws + 0x22000);
    int*            tok    = (int*)(ws + 0x23000);
    float*          wgt    = (float*)(ws + 0x2B000);
    unsigned short* act    = (unsigned short*)(ws + 0x33000);   // 12.6 MB
    __bf16*         xb     = (__bf16*)(ws + 0xC40000);          // 4 MB

    // zero d_out with a proper grid (graph memset node ran at 35 GB/s, ~230 us)
    zero_kernel<<<(T_TOK * H_DIM) / (256 * 4), 256, 0, stream>>>(out);

    cvtx_kernel<<<(T_TOK * H_DIM) / (256 * 8), 256, 0, stream>>>(x, xb);
    router_kernel<<<T_TOK, 256, 0, stream>>>(x, gw, wdense, masks);
    count_kernel<<<E_NUM, 256, 0, stream>>>(masks, cnt);
    scan_kernel<<<1, 64, 0, stream>>>(cnt, off, tbl);
    fill_kernel<<<E_NUM, 256, 0, stream>>>(masks, wdense, off, tok, wgt);
    gemm1_kernel<<<GRID_P, 256, 0, stream>>>(xb, w13, tok, cnt, off, tbl, act);
    gemm2_kernel<<<GRID_P, 256, 0, stream>>>(act, w2, tok, wgt, cnt, off, tbl, out);
}